// Round 5
// baseline (3913.612 us; speedup 1.0000x reference)
//
#include <hip/hip_runtime.h>
#include <stdint.h>

#define TOKENS 4096
#define DMODEL 1024
#define VOCAB  32000
#define KSEL   128

#define BM 128
#define BN 128
#define BK 64

#define NB  2048   // histogram bins
#define CUT (NB/4) // speculative gather cutoff (bins strictly below)
#define CAP 2048   // gather capacity

typedef __attribute__((ext_vector_type(8))) short short8;
typedef __attribute__((ext_vector_type(4))) float f32x4;
typedef __attribute__((ext_vector_type(4))) unsigned int uint32x4;

__device__ __forceinline__ unsigned short f2bf(float f) {
  uint32_t u = __float_as_uint(f);
  uint32_t r = (u + 0x7fffu + ((u >> 16) & 1u)) >> 16;
  return (unsigned short)r;
}
// order-preserving float<->uint for atomicMin/Max
__device__ __forceinline__ unsigned encf(float f) {
  unsigned u = __float_as_uint(f);
  return (u >> 31) ? ~u : (u | 0x80000000u);
}
__device__ __forceinline__ float decf(unsigned e) {
  return __uint_as_float((e >> 31) ? (e & 0x7fffffffu) : ~e);
}

// ---------------- fp32 -> bf16 cast + fp32 row sum-of-squares ----------------
__global__ __launch_bounds__(256)
void conv_rows(const float* __restrict__ src, unsigned short* __restrict__ dst,
               float* __restrict__ sq, int nrows) {
  int row = blockIdx.x;
  int t = threadIdx.x;
  const float4* s4 = (const float4*)(src + (size_t)row * DMODEL);
  float4 v = s4[t];                      // DMODEL/4 == 256 == blockDim
  float ss = v.x*v.x + v.y*v.y + v.z*v.z + v.w*v.w;
  uint2 pk;
  pk.x = (uint32_t)f2bf(v.x) | ((uint32_t)f2bf(v.y) << 16);
  pk.y = (uint32_t)f2bf(v.z) | ((uint32_t)f2bf(v.w) << 16);
  ((uint2*)(dst + (size_t)row * DMODEL))[t] = pk;

  __shared__ float red[256];
  red[t] = ss; __syncthreads();
  for (int s = 128; s > 0; s >>= 1) {
    if (t < s) red[t] += red[t + s];
    __syncthreads();
  }
  if (t == 0) sq[row] = red[0];
}

// ---------------- bf16 MFMA GEMM with fused distance epilogue ----------------
// dist[rowL][v] = bf16( xsq[row] + bsq[v] - 2 * (x . w) ), plus GLOBAL min/max
__global__ __launch_bounds__(256)
void gemm_dist(const unsigned short* __restrict__ Xb,
               const unsigned short* __restrict__ Wb,
               const float* __restrict__ xsq, const float* __restrict__ bsq,
               unsigned short* __restrict__ dist,
               unsigned* __restrict__ gmnE, unsigned* __restrict__ gmxE,
               int row0) {
  __shared__ unsigned short S[BM * BK * 2];   // 32 KB: A|B tiles, then C restage
  unsigned short* As = S;
  unsigned short* Bs = S + BM * BK;
  __shared__ unsigned wmn[4], wmx[4];

  int tid  = threadIdx.x;
  int lane = tid & 63;
  int wid  = tid >> 6;        // 4 waves, 2x2
  int wr   = wid >> 1;
  int wc   = wid & 1;

  // ---- XCD-aware bijective swizzle + 4-row supertiles ----
  int nwg = gridDim.x * gridDim.y;               // multiple of 8 for all TS
  int bid = blockIdx.y * gridDim.x + blockIdx.x;
  int cpx = nwg >> 3;
  int o   = (bid & 7) * cpx + (bid >> 3);        // bijective (nwg%8==0)
  int NR  = gridDim.y;
  int GR  = (NR & 3) ? 1 : 4;                    // row-group size
  int span = gridDim.x * GR;
  int sg  = o / span;
  int rem = o - sg * span;
  int bn  = rem / GR;
  int bm  = sg * GR + (rem - bn * GR);

  int rowBase = row0 + bm * BM;       // global token row base
  int colBase = bn * BN;              // vocab base

  f32x4 acc[4][4];
#pragma unroll
  for (int m = 0; m < 4; m++)
#pragma unroll
    for (int n = 0; n < 4; n++) acc[m][n] = (f32x4){0.f, 0.f, 0.f, 0.f};

  const unsigned short* Ag = Xb + (size_t)rowBase * DMODEL;
  const unsigned short* Bg = Wb + (size_t)colBase * DMODEL;

  int r16 = lane & 15;
  int kg  = lane >> 4;

  for (int kt = 0; kt < DMODEL; kt += BK) {
    // stage 128x64 bf16 A and B tiles via async global->LDS, 16B/lane
#pragma unroll
    for (int c = 0; c < 4; c++) {
      int g   = (c * 4 + wid) * 64 + lane;   // 16B granule id, 0..1023
      int r   = g >> 3;                      // tile row 0..127
      int col = (g & 7) * 8;                 // tile col (bf16 elems)
      const unsigned short* ga = Ag + (size_t)r * DMODEL + kt + col;
      const unsigned short* gb = Bg + (size_t)r * DMODEL + kt + col;
      int chunkElems = (c * 4 + wid) * 512;  // wave-uniform LDS chunk base
      __builtin_amdgcn_global_load_lds(
          (const __attribute__((address_space(1))) void*)ga,
          (__attribute__((address_space(3))) void*)(&As[chunkElems]), 16, 0, 0);
      __builtin_amdgcn_global_load_lds(
          (const __attribute__((address_space(1))) void*)gb,
          (__attribute__((address_space(3))) void*)(&Bs[chunkElems]), 16, 0, 0);
    }
    __syncthreads();

#pragma unroll
    for (int kk = 0; kk < BK; kk += 32) {
      short8 a[4], b[4];
#pragma unroll
      for (int m = 0; m < 4; m++)
        a[m] = *(const short8*)&As[(wr * 64 + m * 16 + r16) * BK + kk + kg * 8];
#pragma unroll
      for (int n = 0; n < 4; n++)
        b[n] = *(const short8*)&Bs[(wc * 64 + n * 16 + r16) * BK + kk + kg * 8];
#pragma unroll
      for (int m = 0; m < 4; m++)
#pragma unroll
        for (int n = 0; n < 4; n++)
          acc[m][n] = __builtin_amdgcn_mfma_f32_16x16x32_bf16(a[m], b[n], acc[m][n], 0, 0, 0);
    }
    __syncthreads();
  }

  // ---- epilogue: distances -> bf16 into LDS (swizzled), track min/max ----
  // C/D layout: col=lane&15, row=(lane>>4)*4+i
  int col16 = lane & 15;
  int rg    = lane >> 4;
  float bq[4];
#pragma unroll
  for (int n = 0; n < 4; n++) bq[n] = bsq[colBase + wc * 64 + n * 16 + col16];

  float mnT = 3.4e38f, mxT = -3.4e38f;
#pragma unroll
  for (int m = 0; m < 4; m++) {
#pragma unroll
    for (int i = 0; i < 4; i++) {
      int row = wr * 64 + m * 16 + rg * 4 + i;        // block-local row
      float xq = xsq[rowBase + row];
#pragma unroll
      for (int n = 0; n < 4; n++) {
        float d = xq + bq[n] - 2.0f * acc[m][n][i];
        unsigned short h = f2bf(d);
        float dr = __uint_as_float((unsigned)h << 16);
        mnT = fminf(mnT, dr);
        mxT = fmaxf(mxT, dr);
        int col = wc * 64 + n * 16 + col16;
        int byte = (row << 8) + (col << 1);
        byte ^= (row & 12) << 3;                      // bank swizzle
        *(unsigned short*)((char*)S + byte) = h;
      }
    }
  }
#pragma unroll
  for (int off = 32; off; off >>= 1) {
    mnT = fminf(mnT, __shfl_xor(mnT, off));
    mxT = fmaxf(mxT, __shfl_xor(mxT, off));
  }
  if (lane == 0) { wmn[wid] = encf(mnT); wmx[wid] = encf(mxT); }
  __syncthreads();
  if (tid == 0) {
    unsigned a = min(min(wmn[0], wmn[1]), min(wmn[2], wmn[3]));
    unsigned b = max(max(wmx[0], wmx[1]), max(wmx[2], wmx[3]));
    atomicMin(gmnE, a);
    atomicMax(gmxE, b);
  }

  // ---- coalesced 16B non-temporal stores from LDS ----
  size_t gbase = (size_t)(bm * BM) * VOCAB + colBase;
#pragma unroll
  for (int c = 0; c < 8; c++) {
    int g   = c * 256 + tid;            // 16B granule, 0..2047
    int row = g >> 4;
    int byte = (row << 8) + ((g & 15) << 4);
    byte ^= (row & 12) << 3;
    uint32x4 v = *(const uint32x4*)((const char*)S + byte);
    __builtin_nontemporal_store(
        v, (uint32x4*)(dist + gbase + (size_t)row * VOCAB + ((g & 15) << 3)));
  }
}

// ---------------- per-row 128-smallest, sorted ascending ----------------
__device__ __forceinline__ int binOf(float x, float mn, float invw) {
  int b = (int)((x - mn) * invw);
  b = b < 0 ? 0 : b;
  return b < NB - 1 ? b : NB - 1;
}

__device__ __forceinline__ void scanFind(unsigned* bins, unsigned* s_scan,
                                         unsigned target, int* s_B,
                                         unsigned* s_cum, int t) {
  unsigned ssum = 0;
  int base = t * (NB / 256);
#pragma unroll
  for (int j = 0; j < NB / 256; j++) ssum += bins[base + j];
  s_scan[t] = ssum;
  __syncthreads();
  for (int off = 1; off < 256; off <<= 1) {
    unsigned add = (t >= off) ? s_scan[t - off] : 0u;
    __syncthreads();
    s_scan[t] += add;
    __syncthreads();
  }
  unsigned incl = s_scan[t];
  unsigned excl = incl - ssum;
  if (excl < target && incl >= target) {
    unsigned cum = excl;
    for (int j = 0; j < NB / 256; j++) {
      cum += bins[base + j];
      if (cum >= target) { *s_B = base + j; *s_cum = cum; break; }
    }
  }
  __syncthreads();
}

__global__ __launch_bounds__(256)
void select_topk(const unsigned short* __restrict__ dist,
                 const unsigned* __restrict__ gmnE,
                 const unsigned* __restrict__ gmxE,
                 float* __restrict__ out, int row0) {
  int r = blockIdx.x;
  int t = threadIdx.x;
  int grow = row0 + r;
  const unsigned short* rowp = dist + (size_t)r * VOCAB;

  __shared__ unsigned s_scan[256];
  __shared__ unsigned bins[NB];
  __shared__ float    cand[CAP];
  __shared__ unsigned s_cnt;
  __shared__ int      s_B;
  __shared__ unsigned s_cum;

  float rmn = decf(gmnE[0]);
  float rmx = decf(gmxE[0]);
  float range = rmx - rmn;

  if (!(range > 1e-20f)) {   // degenerate: all values equal
    for (int i = t; i < KSEL; i += 256)
      out[(size_t)grow * KSEL + i] = rmn;
    return;
  }
  float invw = (float)NB / range;

  // pass 1: histogram + speculative gather (bins < CUT)
  for (int i = t; i < NB; i += 256) bins[i] = 0;
  if (t == 0) s_cnt = 0;
  __syncthreads();
  const uint4* rp4 = (const uint4*)rowp;   // 8 bf16 per load
  for (int i = t; i < VOCAB / 8; i += 256) {
    uint4 u = rp4[i];
    unsigned w[4] = {u.x, u.y, u.z, u.w};
#pragma unroll
    for (int j = 0; j < 4; j++) {
#pragma unroll
      for (int h = 0; h < 2; h++) {
        float x = __uint_as_float(h ? (w[j] & 0xffff0000u) : (w[j] << 16));
        int b = binOf(x, rmn, invw);
        atomicAdd(&bins[b], 1u);
        if (b < CUT) {
          unsigned idx = atomicAdd(&s_cnt, 1u);
          if (idx < CAP) cand[idx] = x;
        }
      }
    }
  }
  __syncthreads();

  scanFind(bins, s_scan, KSEL, &s_B, &s_cum, t);
  int B = s_B;
  bool specOK = (B < CUT) && (s_cnt <= CAP);

  if (!specOK) {
    // exact gather pass (<= bin B)
    __syncthreads();
    if (t == 0) s_cnt = 0;
    __syncthreads();
    for (int i = t; i < VOCAB / 8; i += 256) {
      uint4 u = rp4[i];
      unsigned w[4] = {u.x, u.y, u.z, u.w};
#pragma unroll
      for (int j = 0; j < 4; j++) {
#pragma unroll
        for (int h = 0; h < 2; h++) {
          float x = __uint_as_float(h ? (w[j] & 0xffff0000u) : (w[j] << 16));
          if (binOf(x, rmn, invw) <= B) {
            unsigned idx = atomicAdd(&s_cnt, 1u);
            if (idx < CAP) cand[idx] = x;
          }
        }
      }
    }
    __syncthreads();
  }
  int m = (int)(s_cnt < CAP ? s_cnt : CAP);

  // rank + scatter (ascending). ranks unique via index tie-break.
  // Spec path: cand is a superset of the true top-K; every value smaller than
  // a top-K element is guaranteed present (bin <= B < CUT), so ranks < KSEL
  // are exact.
  for (int i = t; i < m; i += 256) {
    float vi = cand[i];
    int rk = 0;
    for (int j = 0; j < m; j++) {
      float vj = cand[j];
      rk += (vj < vi) || (vj == vi && j < i);
    }
    if (rk < KSEL) out[(size_t)grow * KSEL + rk] = vi;
  }
}

extern "C" void kernel_launch(void* const* d_in, const int* in_sizes, int n_in,
                              void* d_out, int out_size, void* d_ws, size_t ws_size,
                              hipStream_t stream) {
  const float* x = (const float*)d_in[0];
  const float* w = (const float*)d_in[1];
  float* out = (float*)d_out;

  char* ws = (char*)d_ws;
  size_t off = 0;
  auto alloc = [&](size_t bytes) -> char* {
    off = (off + 255) & ~(size_t)255;
    char* p = ws + off;
    off += bytes;
    return p;
  };
  unsigned short* Xb = (unsigned short*)alloc((size_t)TOKENS * DMODEL * 2);
  unsigned short* Wb = (unsigned short*)alloc((size_t)VOCAB * DMODEL * 2);
  float* xsq = (float*)alloc((size_t)TOKENS * 4);
  float* bsq = (float*)alloc((size_t)VOCAB * 4);
  unsigned* gmnE = (unsigned*)alloc(4);
  unsigned* gmxE = (unsigned*)alloc(4);
  off = (off + 255) & ~(size_t)255;
  size_t fixed = off;

  // dist slab: TS * VOCAB * 2 bytes (bf16). TS=512 -> 33 MB slab; nt stores
  // keep the stream out of L3 so W (65 MB) stays cache-resident.
  int TS = 512;
  while (TS > 128 && fixed + (size_t)TS * VOCAB * 2 > ws_size) TS >>= 1;
  unsigned short* dist = (unsigned short*)(ws + fixed);

  (void)hipMemsetAsync(gmnE, 0xFF, 4, stream);   // +inf encoding
  (void)hipMemsetAsync(gmxE, 0x00, 4, stream);   // -inf encoding

  conv_rows<<<TOKENS, 256, 0, stream>>>(x, Xb, xsq, TOKENS);
  conv_rows<<<VOCAB, 256, 0, stream>>>(w, Wb, bsq, VOCAB);

  for (int row0 = 0; row0 < TOKENS; row0 += TS) {
    dim3 g(VOCAB / BN, TS / BM);
    gemm_dist<<<g, 256, 0, stream>>>(Xb, Wb, xsq, bsq, dist, gmnE, gmxE, row0);
    select_topk<<<TS, 256, 0, stream>>>(dist, gmnE, gmxE, out, row0);
  }
}

// Round 6
// 841.924 us; speedup vs baseline: 4.6484x; 4.6484x over previous
//
#include <hip/hip_runtime.h>
#include <stdint.h>

#define TOKENS 4096
#define DMODEL 1024
#define VOCAB  32000
#define KSEL   128

#define BM 128
#define BN 128
#define BK 64

#define NB 4096            // bf16-key histogram bins
#define KEY_BASE 0x3F80    // bf16 bit pattern of 1.0f

typedef __attribute__((ext_vector_type(8))) short short8;
typedef __attribute__((ext_vector_type(4))) float f32x4;
typedef __attribute__((ext_vector_type(4))) unsigned int uint32x4;

__device__ __forceinline__ unsigned short f2bf(float f) {
  uint32_t u = __float_as_uint(f);
  uint32_t r = (u + 0x7fffu + ((u >> 16) & 1u)) >> 16;
  return (unsigned short)r;
}

// ---------------- fp32 -> bf16 cast + fp32 row sum-of-squares ----------------
__global__ __launch_bounds__(256)
void conv_rows(const float* __restrict__ src, unsigned short* __restrict__ dst,
               float* __restrict__ sq, int nrows) {
  int row = blockIdx.x;
  int t = threadIdx.x;
  const float4* s4 = (const float4*)(src + (size_t)row * DMODEL);
  float4 v = s4[t];                      // DMODEL/4 == 256 == blockDim
  float ss = v.x*v.x + v.y*v.y + v.z*v.z + v.w*v.w;
  uint2 pk;
  pk.x = (uint32_t)f2bf(v.x) | ((uint32_t)f2bf(v.y) << 16);
  pk.y = (uint32_t)f2bf(v.z) | ((uint32_t)f2bf(v.w) << 16);
  ((uint2*)(dst + (size_t)row * DMODEL))[t] = pk;

  __shared__ float red[256];
  red[t] = ss; __syncthreads();
  for (int s = 128; s > 0; s >>= 1) {
    if (t < s) red[t] += red[t + s];
    __syncthreads();
  }
  if (t == 0) sq[row] = red[0];
}

// ---------------- bf16 MFMA GEMM with fused distance epilogue ----------------
// dist[rowL][v] = bf16( xsq[row] + bsq[v] - 2 * (x . w) )
__global__ __launch_bounds__(256)
void gemm_dist(const unsigned short* __restrict__ Xb,
               const unsigned short* __restrict__ Wb,
               const float* __restrict__ xsq, const float* __restrict__ bsq,
               unsigned short* __restrict__ dist, int row0) {
  __shared__ unsigned short S[BM * BK * 2];   // 32 KB: A|B tiles, then C restage
  unsigned short* As = S;
  unsigned short* Bs = S + BM * BK;

  int tid  = threadIdx.x;
  int lane = tid & 63;
  int wid  = tid >> 6;        // 4 waves, 2x2
  int wr   = wid >> 1;
  int wc   = wid & 1;

  // ---- XCD-aware bijective swizzle + 4-row supertiles ----
  int nwg = gridDim.x * gridDim.y;               // multiple of 8 for all TS
  int bid = blockIdx.y * gridDim.x + blockIdx.x;
  int cpx = nwg >> 3;
  int o   = (bid & 7) * cpx + (bid >> 3);        // bijective (nwg%8==0)
  int NR  = gridDim.y;
  int GR  = (NR & 3) ? 1 : 4;                    // row-group size
  int span = gridDim.x * GR;
  int sg  = o / span;
  int rem = o - sg * span;
  int bn  = rem / GR;
  int bm  = sg * GR + (rem - bn * GR);

  int rowBase = row0 + bm * BM;       // global token row base
  int colBase = bn * BN;              // vocab base

  f32x4 acc[4][4];
#pragma unroll
  for (int m = 0; m < 4; m++)
#pragma unroll
    for (int n = 0; n < 4; n++) acc[m][n] = (f32x4){0.f, 0.f, 0.f, 0.f};

  const unsigned short* Ag = Xb + (size_t)rowBase * DMODEL;
  const unsigned short* Bg = Wb + (size_t)colBase * DMODEL;

  int r16 = lane & 15;
  int kg  = lane >> 4;

  for (int kt = 0; kt < DMODEL; kt += BK) {
    // stage 128x64 bf16 A and B tiles via async global->LDS, 16B/lane
#pragma unroll
    for (int c = 0; c < 4; c++) {
      int g   = (c * 4 + wid) * 64 + lane;   // 16B granule id, 0..1023
      int r   = g >> 3;                      // tile row 0..127
      int col = (g & 7) * 8;                 // tile col (bf16 elems)
      const unsigned short* ga = Ag + (size_t)r * DMODEL + kt + col;
      const unsigned short* gb = Bg + (size_t)r * DMODEL + kt + col;
      int chunkElems = (c * 4 + wid) * 512;  // wave-uniform LDS chunk base
      __builtin_amdgcn_global_load_lds(
          (const __attribute__((address_space(1))) void*)ga,
          (__attribute__((address_space(3))) void*)(&As[chunkElems]), 16, 0, 0);
      __builtin_amdgcn_global_load_lds(
          (const __attribute__((address_space(1))) void*)gb,
          (__attribute__((address_space(3))) void*)(&Bs[chunkElems]), 16, 0, 0);
    }
    __syncthreads();

#pragma unroll
    for (int kk = 0; kk < BK; kk += 32) {
      short8 a[4], b[4];
#pragma unroll
      for (int m = 0; m < 4; m++)
        a[m] = *(const short8*)&As[(wr * 64 + m * 16 + r16) * BK + kk + kg * 8];
#pragma unroll
      for (int n = 0; n < 4; n++)
        b[n] = *(const short8*)&Bs[(wc * 64 + n * 16 + r16) * BK + kk + kg * 8];
#pragma unroll
      for (int m = 0; m < 4; m++)
#pragma unroll
        for (int n = 0; n < 4; n++)
          acc[m][n] = __builtin_amdgcn_mfma_f32_16x16x32_bf16(a[m], b[n], acc[m][n], 0, 0, 0);
    }
    __syncthreads();
  }

  // ---- epilogue: distances -> bf16 into LDS (swizzled) ----
  // C/D layout: col=lane&15, row=(lane>>4)*4+i
  int col16 = lane & 15;
  int rg    = lane >> 4;
  float bq[4];
#pragma unroll
  for (int n = 0; n < 4; n++) bq[n] = bsq[colBase + wc * 64 + n * 16 + col16];

#pragma unroll
  for (int m = 0; m < 4; m++) {
#pragma unroll
    for (int i = 0; i < 4; i++) {
      int row = wr * 64 + m * 16 + rg * 4 + i;        // block-local row
      float xq = xsq[rowBase + row];
#pragma unroll
      for (int n = 0; n < 4; n++) {
        float d = xq + bq[n] - 2.0f * acc[m][n][i];
        unsigned short h = f2bf(d);
        int col = wc * 64 + n * 16 + col16;
        int byte = (row << 8) + (col << 1);
        byte ^= (row & 12) << 3;                      // bank swizzle
        *(unsigned short*)((char*)S + byte) = h;
      }
    }
  }
  __syncthreads();

  // ---- coalesced 16B non-temporal stores from LDS ----
  size_t gbase = (size_t)(bm * BM) * VOCAB + colBase;
#pragma unroll
  for (int c = 0; c < 8; c++) {
    int g   = c * 256 + tid;            // 16B granule, 0..2047
    int row = g >> 4;
    int byte = (row << 8) + ((g & 15) << 4);
    byte ^= (row & 12) << 3;
    uint32x4 v = *(const uint32x4*)((const char*)S + byte);
    __builtin_nontemporal_store(
        v, (uint32x4*)(dist + gbase + (size_t)row * VOCAB + ((g & 15) << 3)));
  }
}

// ---------------- per-row exact 128-smallest via bf16-key histogram ----------
// Keys are bf16 bit patterns (all distances > 0 -> unsigned key order ==
// float order). bin = key - KEY_BASE clamped to [0, NB): covers [1.0, 2e9],
// data sits ~2000, so no real value ever clamps.
__global__ __launch_bounds__(256)
void select_topk(const unsigned short* __restrict__ dist,
                 float* __restrict__ out, int row0) {
  int r = blockIdx.x;
  int t = threadIdx.x;
  int grow = row0 + r;
  const unsigned short* rowp = dist + (size_t)r * VOCAB;

  __shared__ unsigned bins[NB];       // 16 KB
  __shared__ unsigned s_scan[256];
  __shared__ float    cand[KSEL];     // < 128 strictly-below-threshold values
  __shared__ unsigned s_cnt;
  __shared__ int      s_T;
  __shared__ unsigned s_cum;

  for (int i = t; i < NB; i += 256) bins[i] = 0;
  if (t == 0) { s_cnt = 0; s_T = NB - 1; s_cum = VOCAB; }
  __syncthreads();

  // pass 1: histogram on bf16 keys
  const uint4* rp4 = (const uint4*)rowp;   // 8 bf16 per load
  for (int i = t; i < VOCAB / 8; i += 256) {
    uint4 u = rp4[i];
    unsigned w[4] = {u.x, u.y, u.z, u.w};
#pragma unroll
    for (int j = 0; j < 4; j++) {
      int b0 = (int)(w[j] & 0xffffu) - KEY_BASE;
      int b1 = (int)(w[j] >> 16) - KEY_BASE;
      b0 = b0 < 0 ? 0 : (b0 > NB - 1 ? NB - 1 : b0);
      b1 = b1 < 0 ? 0 : (b1 > NB - 1 ? NB - 1 : b1);
      atomicAdd(&bins[b0], 1u);
      atomicAdd(&bins[b1], 1u);
    }
  }
  __syncthreads();

  // scan: first bin T with cum >= KSEL
  {
    unsigned ssum = 0;
    int base = t * (NB / 256);
#pragma unroll
    for (int j = 0; j < NB / 256; j++) ssum += bins[base + j];
    s_scan[t] = ssum;
    __syncthreads();
    for (int off = 1; off < 256; off <<= 1) {
      unsigned add = (t >= off) ? s_scan[t - off] : 0u;
      __syncthreads();
      s_scan[t] += add;
      __syncthreads();
    }
    unsigned incl = s_scan[t];
    unsigned excl = incl - ssum;
    if (excl < KSEL && incl >= KSEL) {
      unsigned cum = excl;
      for (int j = 0; j < NB / 256; j++) {
        cum += bins[base + j];
        if (cum >= KSEL) { s_T = base + j; s_cum = cum; break; }
      }
    }
    __syncthreads();
  }
  int T = s_T;
  unsigned less = s_cum - bins[T];             // strictly below bin T, < 128
  unsigned short Tkey = (unsigned short)(T + KEY_BASE);
  float Tval = __uint_as_float((unsigned)Tkey << 16);
  __syncthreads();

  // pass 2: gather values with key < Tkey (exactly `less` of them)
  for (int i = t; i < VOCAB / 8; i += 256) {
    uint4 u = rp4[i];
    unsigned w[4] = {u.x, u.y, u.z, u.w};
#pragma unroll
    for (int j = 0; j < 4; j++) {
#pragma unroll
      for (int h = 0; h < 2; h++) {
        unsigned short key = (unsigned short)(h ? (w[j] >> 16) : (w[j] & 0xffffu));
        if (key < Tkey) {
          unsigned idx = atomicAdd(&s_cnt, 1u);
          if (idx < KSEL) cand[idx] = __uint_as_float((unsigned)key << 16);
        }
      }
    }
  }
  __syncthreads();
  int m = (int)(s_cnt < (unsigned)KSEL ? s_cnt : (unsigned)KSEL);
  (void)less;

  // rank + scatter ascending (m < 128 -> one candidate per thread)
  if (t < m) {
    float vi = cand[t];
    int rk = 0;
    for (int j = 0; j < m; j++) {
      float vj = cand[j];
      rk += (vj < vi) || (vj == vi && j < t);
    }
    out[(size_t)grow * KSEL + rk] = vi;
  }
  // fill the tail with the threshold value
  for (int i = m + t; i < KSEL; i += 256)
    out[(size_t)grow * KSEL + i] = Tval;
}

extern "C" void kernel_launch(void* const* d_in, const int* in_sizes, int n_in,
                              void* d_out, int out_size, void* d_ws, size_t ws_size,
                              hipStream_t stream) {
  const float* x = (const float*)d_in[0];
  const float* w = (const float*)d_in[1];
  float* out = (float*)d_out;

  char* ws = (char*)d_ws;
  size_t off = 0;
  auto alloc = [&](size_t bytes) -> char* {
    off = (off + 255) & ~(size_t)255;
    char* p = ws + off;
    off += bytes;
    return p;
  };
  unsigned short* Xb = (unsigned short*)alloc((size_t)TOKENS * DMODEL * 2);
  unsigned short* Wb = (unsigned short*)alloc((size_t)VOCAB * DMODEL * 2);
  float* xsq = (float*)alloc((size_t)TOKENS * 4);
  float* bsq = (float*)alloc((size_t)VOCAB * 4);
  off = (off + 255) & ~(size_t)255;
  size_t fixed = off;

  // dist slab: TS * VOCAB * 2 bytes (bf16). TS=512 -> 33 MB slab; nt stores
  // keep the stream out of L3 so W (65 MB) stays cache-resident.
  int TS = 512;
  while (TS > 128 && fixed + (size_t)TS * VOCAB * 2 > ws_size) TS >>= 1;
  unsigned short* dist = (unsigned short*)(ws + fixed);

  conv_rows<<<TOKENS, 256, 0, stream>>>(x, Xb, xsq, TOKENS);
  conv_rows<<<VOCAB, 256, 0, stream>>>(w, Wb, bsq, VOCAB);

  for (int row0 = 0; row0 < TOKENS; row0 += TS) {
    dim3 g(VOCAB / BN, TS / BM);
    gemm_dist<<<g, 256, 0, stream>>>(Xb, Wb, xsq, bsq, dist, row0);
    select_topk<<<TS, 256, 0, stream>>>(dist, out, row0);
  }
}